// Round 1
// 1073.633 us; speedup vs baseline: 1.3468x; 1.3468x over previous
//
#include <hip/hip_runtime.h>

typedef _Float16 f16;
typedef _Float16 f16x8 __attribute__((ext_vector_type(8)));
typedef _Float16 f16x4 __attribute__((ext_vector_type(4)));
typedef float f32x4 __attribute__((ext_vector_type(4)));

// ---------------------------------------------------------------------------
// async 16B global -> LDS copy. LDS dest is wave-uniform base + lane*16;
// per-thread dest pointers base+t*16 satisfy that. Global source is per-lane.
// ---------------------------------------------------------------------------
__device__ __forceinline__ void gload_lds16(const void* g, void* l) {
  __builtin_amdgcn_global_load_lds(
      (const __attribute__((address_space(1))) unsigned int*)g,
      (__attribute__((address_space(3))) unsigned int*)l,
      16, 0, 0);
}

// raw workgroup barrier WITHOUT the vmcnt(0) drain __syncthreads would emit.
// sched_barrier(0) + asm memory fences pin both MIR scheduling and IR-level
// memory movement across the phase boundary (rules #18/#21 discipline).
__device__ __forceinline__ void bar() {
  __builtin_amdgcn_sched_barrier(0);
  asm volatile("" ::: "memory");
  __builtin_amdgcn_s_barrier();
  asm volatile("" ::: "memory");
  __builtin_amdgcn_sched_barrier(0);
}

// ---------------------------------------------------------------------------
// C = scale * A * B^T   (A: M x K row-major, B: N x K row-major, C: M x N)
// 256x256 tile, BK=64, 512 thr = 8 waves (2M x 4N), each wave 128x64 out via
// acc[8][4] of 16x16x32 f16 MFMA. 8-phase schedule, counted vmcnt (T3+T4),
// LDS XOR swizzle both-sides (T2), setprio around MFMA clusters (T5),
// bijective XCD blockIdx swizzle (T1). K must be a multiple of 128.
// ---------------------------------------------------------------------------
template <typename CT>
__global__ __launch_bounds__(512) void gemm_bt256(
    const f16* __restrict__ A, const f16* __restrict__ B, CT* __restrict__ C,
    int K, int lda, int ldb, int ldc,
    long long sAz, long long sBz, long long sCz, float scale)
{
  __shared__ f16 sm[2][2][16384];  // [buf][0=A,1=B][256 rows x 64 cols] 128KiB

  const int t    = threadIdx.x;
  const int lane = t & 63;
  const int wave = t >> 6;
  const int wm   = wave >> 2;   // 0..1
  const int wn   = wave & 3;    // 0..3

  // T1: bijective XCD swizzle (m204) over flattened (x,y)
  const int nx   = (int)gridDim.x;
  const int nwg  = nx * (int)gridDim.y;
  const int orig = (int)blockIdx.y * nx + (int)blockIdx.x;
  const int q8 = nwg >> 3, r8 = nwg & 7;
  const int xcd = orig & 7, loc = orig >> 3;
  const int wg  = (xcd < r8 ? xcd * (q8 + 1) : r8 * (q8 + 1) + (xcd - r8) * q8) + loc;
  const long long bm = (long long)(wg / nx) * 256;
  const long long bn = (long long)(wg % nx) * 256;

  const f16* Ab = A + (long long)blockIdx.z * sAz;
  const f16* Bb = B + (long long)blockIdx.z * sBz;
  CT*        Cb = C + (long long)blockIdx.z * sCz;

  // ---- staging (T2: swizzle the GLOBAL source, keep LDS linear) ----
  // LDS slot c*16B holds global (row = c>>3, colblk = (c&7) ^ (row&7)).
  const int srow = t >> 3;                        // 0..63
  const int scol = ((t & 7) ^ (srow & 7)) << 3;   // swizzled col, f16 elems
  const f16* gA = Ab + (bm + srow) * (long long)lda + scol;
  const f16* gB = Bb + (bn + srow) * (long long)ldb + scol;
  f16* const lA0 = &sm[0][0][0] + t * 8;
  f16* const lB0 = &sm[0][1][0] + t * 8;
  f16* const lA1 = &sm[1][0][0] + t * 8;
  f16* const lB1 = &sm[1][1][0] + t * 8;

  // stage one full 256x64 operand tile: 4 x global_load_lds_dwordx4 / thread
#define STAGE(g, ld, l, kt)                                       \
  { const f16* _g = (g) + (long long)(kt) * 64;                   \
    gload_lds16(_g,                         (l));                 \
    gload_lds16(_g +  64 * (long long)(ld), (l) + 4096);          \
    gload_lds16(_g + 128 * (long long)(ld), (l) + 8192);          \
    gload_lds16(_g + 192 * (long long)(ld), (l) + 12288); }

  // ---- fragment addressing (swizzled ds_read, 2-way conflicts = free) ----
  const int fr  = lane & 15;
  const int c0  = (((lane >> 4))     ^ (lane & 7)) << 3;  // k-step 0
  const int c1  = (((lane >> 4) + 4) ^ (lane & 7)) << 3;  // k-step 1
  const int aro = (wm * 128 + fr) * 64;  // elem offset of lane's A row
  const int bro = (wn * 64  + fr) * 64;  // elem offset of lane's B row
  const f16* const sA[2] = { &sm[0][0][0], &sm[1][0][0] };
  const f16* const sB[2] = { &sm[0][1][0], &sm[1][1][0] };

  f16x8 af[4][2], bf[4][2];
  f32x4 acc[8][4];
  #pragma unroll
  for (int i = 0; i < 8; ++i)
    #pragma unroll
    for (int j = 0; j < 4; ++j)
      acc[i][j] = {0.f, 0.f, 0.f, 0.f};

#define LOAD_A(b, mg)                                             \
  { const f16* _p = sA[b] + aro + (mg) * 4096;                    \
    _Pragma("unroll")                                             \
    for (int mi = 0; mi < 4; ++mi) {                              \
      af[mi][0] = *(const f16x8*)(_p + mi * 1024 + c0);           \
      af[mi][1] = *(const f16x8*)(_p + mi * 1024 + c1);           \
    } }

#define LOAD_B(b, ng)                                             \
  { const f16* _p = sB[b] + bro + (ng) * 2048;                    \
    _Pragma("unroll")                                             \
    for (int ni = 0; ni < 2; ++ni) {                              \
      bf[(ng) * 2 + ni][0] = *(const f16x8*)(_p + ni * 1024 + c0);\
      bf[(ng) * 2 + ni][1] = *(const f16x8*)(_p + ni * 1024 + c1);\
    } }

#define MFMA_Q(mg, ng)                                                        \
  { __builtin_amdgcn_s_setprio(1);                                            \
    _Pragma("unroll")                                                         \
    for (int mi = 0; mi < 4; ++mi)                                            \
      _Pragma("unroll")                                                       \
      for (int ni = 0; ni < 2; ++ni) {                                        \
        acc[(mg)*4+mi][(ng)*2+ni] = __builtin_amdgcn_mfma_f32_16x16x32_f16(   \
            af[mi][0], bf[(ng)*2+ni][0], acc[(mg)*4+mi][(ng)*2+ni], 0, 0, 0); \
        acc[(mg)*4+mi][(ng)*2+ni] = __builtin_amdgcn_mfma_f32_16x16x32_f16(   \
            af[mi][1], bf[(ng)*2+ni][1], acc[(mg)*4+mi][(ng)*2+ni], 0, 0, 0); \
      }                                                                       \
    __builtin_amdgcn_s_setprio(0); }

  // ---- prologue: stage tiles 0 (buf0) and 1 (buf1); wait tile0 landed ----
  STAGE(gA, lda, lA0, 0); STAGE(gB, ldb, lB0, 0);
  STAGE(gA, lda, lA1, 1); STAGE(gB, ldb, lB1, 1);
  asm volatile("s_waitcnt vmcnt(8)" ::: "memory");
  bar();

  // ---- main loop: iteration i computes tiles 2i (buf0), 2i+1 (buf1);
  //      stages tile 2i+2 A@ph4 B@ph5 (buf0), tile 2i+3 A+B@ph8 (buf1).
  // Safety: stages issue only after the closing barrier of the phase in which
  // that buffer-half's reads completed; counted vmcnt+barrier precedes reads.
  const int niter = K / 128;
  #pragma unroll 1
  for (int i = 0; i < niter - 1; ++i) {
    const int kt = 2 * i;
    // ph1: Q(0,0) of tile 2i
    LOAD_A(0, 0); LOAD_B(0, 0);
    bar(); MFMA_Q(0, 0); bar();
    // ph2: Q(0,1)
    LOAD_B(0, 1);
    bar(); MFMA_Q(0, 1); bar();
    // ph3: Q(1,1)
    LOAD_A(0, 1);
    bar(); MFMA_Q(1, 1); bar();
    // ph4: Q(1,0); stage next A into buf0 (buf0 A reads done at ph3-close)
    STAGE(gA, lda, lA0, kt + 2);
    bar(); MFMA_Q(1, 0);
    asm volatile("s_waitcnt vmcnt(4)" ::: "memory");  // tile 2i+1 landed
    bar();
    // ph5: Q(0,0) of tile 2i+1; stage next B into buf0
    LOAD_A(1, 0); LOAD_B(1, 0);
    STAGE(gB, ldb, lB0, kt + 2);
    bar(); MFMA_Q(0, 0); bar();
    // ph6: Q(0,1)
    LOAD_B(1, 1);
    bar(); MFMA_Q(0, 1); bar();
    // ph7: Q(1,1)
    LOAD_A(1, 1);
    bar(); MFMA_Q(1, 1); bar();
    // ph8: Q(1,0); stage tile 2i+3 into buf1 (buf1 reads done at ph7-close)
    STAGE(gA, lda, lA1, kt + 3); STAGE(gB, ldb, lB1, kt + 3);
    bar(); MFMA_Q(1, 0);
    asm volatile("s_waitcnt vmcnt(8)" ::: "memory");  // tile 2i+2 landed
    bar();
  }

  // ---- peeled last iteration (tiles K/64-2, K/64-1): no staging ----
  LOAD_A(0, 0); LOAD_B(0, 0);
  bar(); MFMA_Q(0, 0); bar();
  LOAD_B(0, 1);
  bar(); MFMA_Q(0, 1); bar();
  LOAD_A(0, 1);
  bar(); MFMA_Q(1, 1); bar();
  bar(); MFMA_Q(1, 0);
  asm volatile("s_waitcnt vmcnt(0)" ::: "memory");    // last tile landed
  bar();
  LOAD_A(1, 0); LOAD_B(1, 0);
  bar(); MFMA_Q(0, 0); bar();
  LOAD_B(1, 1);
  bar(); MFMA_Q(0, 1); bar();
  LOAD_A(1, 1);
  bar(); MFMA_Q(1, 1); bar();
  MFMA_Q(1, 0);

#undef STAGE
#undef LOAD_A
#undef LOAD_B
#undef MFMA_Q

  // ---- epilogue: D row=(lane>>4)*4+r, col=lane&15 (verified m89/m91) ----
  const long long crow = bm + wm * 128 + (lane >> 4) * 4;
  const long long ccol = bn + wn * 64 + fr;
  #pragma unroll
  for (int m = 0; m < 8; ++m)
    #pragma unroll
    for (int n = 0; n < 4; ++n)
      #pragma unroll
      for (int r = 0; r < 4; ++r)
        Cb[(crow + m * 16 + r) * ldc + ccol + n * 16] =
            (CT)(acc[m][n][r] * scale);
}

// ---------------------------------------------------------------------------
// row softmax, f16 in/out, IN-PLACE. One 256-thr block per row of T=4096.
// ---------------------------------------------------------------------------
__global__ __launch_bounds__(256) void softmax_rows_f16(
    f16* __restrict__ S, int T)
{
  const size_t row = blockIdx.x;
  const int t      = threadIdx.x;
  f16* s = S + row * (size_t)T;

  f16x8 a = *(const f16x8*)(s + t * 16);
  f16x8 b = *(const f16x8*)(s + t * 16 + 8);

  float v[16];
  float mx = -3.4e38f;
  #pragma unroll
  for (int i = 0; i < 8; ++i) { v[i]     = (float)a[i]; mx = fmaxf(mx, v[i]); }
  #pragma unroll
  for (int i = 0; i < 8; ++i) { v[8 + i] = (float)b[i]; mx = fmaxf(mx, v[8 + i]); }

  __shared__ float red[4];
  #pragma unroll
  for (int o = 32; o > 0; o >>= 1) mx = fmaxf(mx, __shfl_xor(mx, o, 64));
  if ((t & 63) == 0) red[t >> 6] = mx;
  __syncthreads();
  mx = fmaxf(fmaxf(red[0], red[1]), fmaxf(red[2], red[3]));
  __syncthreads();

  float sum = 0.f;
  #pragma unroll
  for (int i = 0; i < 16; ++i) { v[i] = __expf(v[i] - mx); sum += v[i]; }

  #pragma unroll
  for (int o = 32; o > 0; o >>= 1) sum += __shfl_xor(sum, o, 64);
  if ((t & 63) == 0) red[t >> 6] = sum;
  __syncthreads();
  const float inv = 1.f / (red[0] + red[1] + red[2] + red[3]);

  #pragma unroll
  for (int i = 0; i < 8; ++i) a[i] = (f16)(v[i] * inv);
  #pragma unroll
  for (int i = 0; i < 8; ++i) b[i] = (f16)(v[8 + i] * inv);
  *(f16x8*)(s + t * 16)     = a;
  *(f16x8*)(s + t * 16 + 8) = b;
}

// ---------------------------------------------------------------------------
__global__ __launch_bounds__(256) void cvt_f32_f16(
    const float* __restrict__ src, f16* __restrict__ dst, long long n)
{
  long long i = ((long long)blockIdx.x * 256 + threadIdx.x) * 4;
  if (i >= n) return;
  float4 v = *(const float4*)(src + i);
  f16x4 o = {(f16)v.x, (f16)v.y, (f16)v.z, (f16)v.w};
  *(f16x4*)(dst + i) = o;
}

// ---------------------------------------------------------------------------
// Workspace plan:
//   qb  @   0      (64 MiB)  [b][t][h] f16
//   kb  @  64 MiB  (64 MiB)
//   vT  @ 128 MiB  (64 MiB)  [b][h][t] f16
//   xb  @ 192 MiB  (64 MiB)  f16  -- DEAD after projections
//   S   @ 192 MiB  (gs*32 MiB) f16 -- aliases dead xb region
//   wb  @ 192 MiB + max(64, gs*32) MiB  (6 MiB)
// ---------------------------------------------------------------------------
extern "C" void kernel_launch(void* const* d_in, const int* in_sizes, int n_in,
                              void* d_out, int out_size, void* d_ws, size_t ws_size,
                              hipStream_t stream)
{
  const float* x  = (const float*)d_in[0];
  const float* Wq = (const float*)d_in[1];
  const float* Wk = (const float*)d_in[2];
  const float* Wv = (const float*)d_in[3];
  float* out = (float*)d_out;

  const int Bn = 8, T = 4096, Cd = 1024, Hd = 1024;
  const long long BT = (long long)Bn * T;        // 32768

  char* ws = (char*)d_ws;
  const size_t MB = 1u << 20;

  int gs = 0;
  for (int g = 8; g >= 1; g >>= 1) {
    size_t smax = (size_t)(g > 2 ? g * 32 : 64) * MB;
    if (ws_size >= 192 * MB + smax + 6 * MB) { gs = g; break; }
  }
  if (gs == 0) return;
  const size_t sspan = (size_t)(gs > 2 ? gs * 32 : 64) * MB;

  f16* qb  = (f16*)ws;
  f16* kb  = (f16*)(ws + 64 * MB);
  f16* vT  = (f16*)(ws + 128 * MB);              // [b][h][t]
  f16* xb  = (f16*)(ws + 192 * MB);              // dead after projections
  f16* S   = (f16*)(ws + 192 * MB);              // aliases xb
  f16* wqb = (f16*)(ws + 192 * MB + sspan);
  f16* wkb = wqb + (size_t)Hd * Cd;
  f16* wvb = wkb + (size_t)Hd * Cd;

  // 1) fp32 -> f16 converts
  cvt_f32_f16<<<dim3((unsigned)(BT * Cd / 1024)), 256, 0, stream>>>(x, xb, BT * Cd);
  cvt_f32_f16<<<dim3(1024), 256, 0, stream>>>(Wq, wqb, (long long)Hd * Cd);
  cvt_f32_f16<<<dim3(1024), 256, 0, stream>>>(Wk, wkb, (long long)Hd * Cd);
  cvt_f32_f16<<<dim3(1024), 256, 0, stream>>>(Wv, wvb, (long long)Hd * Cd);

  // 2) q = x Wq^T, k = x Wk^T (z-batched: wkb/kb adjacent to wqb/qb)
  gemm_bt256<f16><<<dim3(Hd / 256, (unsigned)(BT / 256), 2), 512, 0, stream>>>(
      xb, wqb, qb, Cd, Cd, Cd, Hd,
      0LL, (long long)Hd * Cd, (long long)BT * Hd, 1.0f);

  // 3) vT_b[h][t] = sum_c Wv[h][c] x_b[t][c]
  gemm_bt256<f16><<<dim3(T / 256, Hd / 256, Bn), 512, 0, stream>>>(
      wvb, xb, vT, Cd, Cd, Cd, T,
      0LL, (long long)T * Cd, (long long)Hd * T, 1.0f);

  // 4-6) attention in batch groups of gs
  for (int b0 = 0; b0 < Bn; b0 += gs) {
    gemm_bt256<f16><<<dim3(T / 256, T / 256, gs), 512, 0, stream>>>(
        qb + (size_t)b0 * T * Hd, kb + (size_t)b0 * T * Hd, S,
        Hd, Hd, Hd, T,
        (long long)T * Hd, (long long)T * Hd, (long long)T * T, 0.03125f);
    softmax_rows_f16<<<dim3((unsigned)(gs * T)), 256, 0, stream>>>(S, T);
    gemm_bt256<float><<<dim3(Hd / 256, T / 256, gs), 512, 0, stream>>>(
        S, vT + (size_t)b0 * Hd * T, out + (size_t)b0 * T * Hd,
        T, T, T, Hd,
        (long long)T * T, (long long)Hd * T, (long long)T * Hd, 1.0f);
  }
  (void)in_sizes; (void)n_in; (void)out_size;
}

// Round 5
// 1051.173 us; speedup vs baseline: 1.3756x; 1.0214x over previous
//
#include <hip/hip_runtime.h>

typedef _Float16 f16;
typedef _Float16 f16x8 __attribute__((ext_vector_type(8)));
typedef _Float16 f16x4 __attribute__((ext_vector_type(4)));
typedef float f32x4 __attribute__((ext_vector_type(4)));

// ---------------------------------------------------------------------------
// async 16B global -> LDS copy. LDS dest is wave-uniform base + lane*16;
// per-thread dest pointers base+t*16 satisfy that. Global source is per-lane.
// ---------------------------------------------------------------------------
__device__ __forceinline__ void gload_lds16(const void* g, void* l) {
  __builtin_amdgcn_global_load_lds(
      (const __attribute__((address_space(1))) unsigned int*)g,
      (__attribute__((address_space(3))) unsigned int*)l,
      16, 0, 0);
}

// ---------------------------------------------------------------------------
// C = scale * A * B^T   (A: M x K row-major, B: N x K row-major, C: M x N)
// 256x256 tile, BK=64, 512 thr = 8 waves (2M x 4N), each wave 128x64 out via
// acc[8][4] of 16x16x32 f16 MFMA. 8-phase schedule. Fencing regime is the
// R1-proven one (sched_barrier(0)+clobbers around s_barrier; compiler-managed
// lgkm waits). Single delta vs R1: stages at earliest-legal phases
// (B@3, A@4, B@7, A@8) with counted VMWAIT(8) at ph4/ph8 -> 4-6 phases of
// HBM-latency cover per stage instead of 3-4. LDS XOR swizzle both-sides
// (T2), setprio around MFMA clusters (T5), bijective XCD swizzle (T1).
// K must be a multiple of 128.
// ---------------------------------------------------------------------------
template <typename CT>
__global__ __launch_bounds__(512) void gemm_bt256(
    const f16* __restrict__ A, const f16* __restrict__ B, CT* __restrict__ C,
    int K, int lda, int ldb, int ldc,
    long long sAz, long long sBz, long long sCz, float scale)
{
  __shared__ f16 sm[2][2][16384];  // [buf][0=A,1=B][256 rows x 64 cols] 128KiB

  const int t    = threadIdx.x;
  const int lane = t & 63;
  const int wave = t >> 6;
  const int wm   = wave >> 2;   // 0..1
  const int wn   = wave & 3;    // 0..3

  // T1: bijective XCD swizzle (m204) over flattened (x,y)
  const int nx   = (int)gridDim.x;
  const int nwg  = nx * (int)gridDim.y;
  const int orig = (int)blockIdx.y * nx + (int)blockIdx.x;
  const int q8 = nwg >> 3, r8 = nwg & 7;
  const int xcd = orig & 7, loc = orig >> 3;
  const int wg  = (xcd < r8 ? xcd * (q8 + 1) : r8 * (q8 + 1) + (xcd - r8) * q8) + loc;
  const long long bm = (long long)(wg / nx) * 256;
  const long long bn = (long long)(wg % nx) * 256;

  const f16* Ab = A + (long long)blockIdx.z * sAz;
  const f16* Bb = B + (long long)blockIdx.z * sBz;
  CT*        Cb = C + (long long)blockIdx.z * sCz;

  // ---- staging (T2: swizzle the GLOBAL source, keep LDS linear) ----
  // LDS slot c*16B holds global (row = c>>3, colblk = (c&7) ^ (row&7)).
  const int srow = t >> 3;                        // 0..63
  const int scol = ((t & 7) ^ (srow & 7)) << 3;   // swizzled col, f16 elems
  const f16* gA = Ab + (bm + srow) * (long long)lda + scol;
  const f16* gB = Bb + (bn + srow) * (long long)ldb + scol;
  f16* const lA0 = &sm[0][0][0] + t * 8;
  f16* const lB0 = &sm[0][1][0] + t * 8;
  f16* const lA1 = &sm[1][0][0] + t * 8;
  f16* const lB1 = &sm[1][1][0] + t * 8;

  // stage one full 256x64 operand tile: 4 x global_load_lds_dwordx4 / thread.
  // clobber first: pin the stage after the preceding barrier (no IR hoist
  // into a region where other waves may still be reading this buffer).
#define STAGE(g, ld, l, kt)                                       \
  { asm volatile("" ::: "memory");                                \
    const f16* _g = (g) + (long long)(kt) * 64;                   \
    gload_lds16(_g,                         (l));                 \
    gload_lds16(_g +  64 * (long long)(ld), (l) + 4096);          \
    gload_lds16(_g + 128 * (long long)(ld), (l) + 8192);          \
    gload_lds16(_g + 192 * (long long)(ld), (l) + 12288); }

  // ---- fragment addressing (swizzled ds_read, 2-way conflicts = free) ----
  const int fr  = lane & 15;
  const int c0  = (((lane >> 4))     ^ (lane & 7)) << 3;  // k-step 0
  const int c1  = (((lane >> 4) + 4) ^ (lane & 7)) << 3;  // k-step 1
  const int aro = (wm * 128 + fr) * 64;  // elem offset of lane's A row
  const int bro = (wn * 64  + fr) * 64;  // elem offset of lane's B row
  const f16* const sA[2] = { &sm[0][0][0], &sm[1][0][0] };
  const f16* const sB[2] = { &sm[0][1][0], &sm[1][1][0] };

  f16x8 af[4][2], bf[4][2];
  f32x4 acc[8][4];
  #pragma unroll
  for (int i = 0; i < 8; ++i)
    #pragma unroll
    for (int j = 0; j < 4; ++j)
      acc[i][j] = {0.f, 0.f, 0.f, 0.f};

#define LOAD_A(b, mg)                                             \
  { const f16* _p = sA[b] + aro + (mg) * 4096;                    \
    _Pragma("unroll")                                             \
    for (int mi = 0; mi < 4; ++mi) {                              \
      af[mi][0] = *(const f16x8*)(_p + mi * 1024 + c0);           \
      af[mi][1] = *(const f16x8*)(_p + mi * 1024 + c1);           \
    } }

#define LOAD_B(b, ng)                                             \
  { const f16* _p = sB[b] + bro + (ng) * 2048;                    \
    _Pragma("unroll")                                             \
    for (int ni = 0; ni < 2; ++ni) {                              \
      bf[(ng) * 2 + ni][0] = *(const f16x8*)(_p + ni * 1024 + c0);\
      bf[(ng) * 2 + ni][1] = *(const f16x8*)(_p + ni * 1024 + c1);\
    } }

#define MFMA_Q(mg, ng)                                                        \
  { __builtin_amdgcn_s_setprio(1);                                            \
    _Pragma("unroll")                                                         \
    for (int mi = 0; mi < 4; ++mi)                                            \
      _Pragma("unroll")                                                       \
      for (int ni = 0; ni < 2; ++ni) {                                        \
        acc[(mg)*4+mi][(ng)*2+ni] = __builtin_amdgcn_mfma_f32_16x16x32_f16(   \
            af[mi][0], bf[(ng)*2+ni][0], acc[(mg)*4+mi][(ng)*2+ni], 0, 0, 0); \
        acc[(mg)*4+mi][(ng)*2+ni] = __builtin_amdgcn_mfma_f32_16x16x32_f16(   \
            af[mi][1], bf[(ng)*2+ni][1], acc[(mg)*4+mi][(ng)*2+ni], 0, 0, 0); \
      }                                                                       \
    __builtin_amdgcn_s_setprio(0); }

  // R1-proven barrier: sched_barrier pins MIR motion, clobbers pin IR motion.
#define BAR()                                  \
  { __builtin_amdgcn_sched_barrier(0);         \
    asm volatile("" ::: "memory");             \
    __builtin_amdgcn_s_barrier();              \
    asm volatile("" ::: "memory");             \
    __builtin_amdgcn_sched_barrier(0); }
#define VMWAIT(n) asm volatile("s_waitcnt vmcnt(" #n ")" ::: "memory")

  // ---- prologue: stage tiles 0 (buf0) and 1 (buf1); wait tile0 landed ----
  STAGE(gB, ldb, lB0, 0); STAGE(gA, lda, lA0, 0);
  STAGE(gB, ldb, lB1, 1); STAGE(gA, lda, lA1, 1);
  VMWAIT(8);
  BAR();

  // ---- main loop: iteration i computes tiles 2i (buf0, ph1-4) and 2i+1
  // (buf1, ph5-8); stages tile 2i+2 (B@ph3, A@ph4 -> buf0) and tile 2i+3
  // (B@ph7, A@ph8 -> buf1). Quadrant order (0,0),(0,1),(1,1),(1,0) frees
  // B-buf at ph3-open and A-buf at ph4-open (every wave's reads of that
  // buffer half completed before the closing barrier of the prior phase).
  // vmcnt ledger (4 loads per STAGE): loop-top outstanding = 8 (prev-iter
  // ph7+ph8). ph3 +4 -> 12, ph4 +4 -> 16; VMWAIT(8) drains prev-iter 8 =>
  // buf1 valid before ph5 reads (4-5 phases cover). ph7/ph8 +8 -> 16;
  // VMWAIT(8) drains ph3+ph4 => buf0 valid for next iter (4-5 phases cover).
  const int niter = K / 128;
  #pragma unroll 1
  for (int i = 0; i < niter - 1; ++i) {
    const int kt = 2 * i;
    // ph1
    LOAD_A(0, 0); LOAD_B(0, 0);
    BAR(); MFMA_Q(0, 0); BAR();
    // ph2
    LOAD_B(0, 1);
    BAR(); MFMA_Q(0, 1); BAR();
    // ph3: B-buf0 free (all B reads done by ph2-close) -> stage next B
    LOAD_A(0, 1);
    STAGE(gB, ldb, lB0, kt + 2);
    BAR(); MFMA_Q(1, 1); BAR();
    // ph4: A-buf0 free (all A reads done by ph3-close) -> stage next A;
    //      then wait for buf1 (tile 2i+1, staged prev-iter ph7/ph8)
    STAGE(gA, lda, lA0, kt + 2);
    BAR(); MFMA_Q(1, 0);
    VMWAIT(8);
    BAR();
    // ph5
    LOAD_A(1, 0); LOAD_B(1, 0);
    BAR(); MFMA_Q(0, 0); BAR();
    // ph6
    LOAD_B(1, 1);
    BAR(); MFMA_Q(0, 1); BAR();
    // ph7: B-buf1 free -> stage next B
    LOAD_A(1, 1);
    STAGE(gB, ldb, lB1, kt + 3);
    BAR(); MFMA_Q(1, 1); BAR();
    // ph8: A-buf1 free -> stage next A; wait for buf0 (tile 2i+2)
    STAGE(gA, lda, lA1, kt + 3);
    BAR(); MFMA_Q(1, 0);
    VMWAIT(8);
    BAR();
  }

  // ---- peeled last iteration (tiles K/64-2, K/64-1): no staging ----
  LOAD_A(0, 0); LOAD_B(0, 0);
  BAR(); MFMA_Q(0, 0); BAR();
  LOAD_B(0, 1);
  BAR(); MFMA_Q(0, 1); BAR();
  LOAD_A(0, 1);
  BAR(); MFMA_Q(1, 1); BAR();
  MFMA_Q(1, 0);
  VMWAIT(0);
  BAR();
  LOAD_A(1, 0); LOAD_B(1, 0);
  BAR(); MFMA_Q(0, 0); BAR();
  LOAD_B(1, 1);
  BAR(); MFMA_Q(0, 1); BAR();
  LOAD_A(1, 1);
  BAR(); MFMA_Q(1, 1); BAR();
  MFMA_Q(1, 0);

#undef STAGE
#undef LOAD_A
#undef LOAD_B
#undef MFMA_Q
#undef BAR
#undef VMWAIT

  // ---- epilogue: D row=(lane>>4)*4+r, col=lane&15 (verified m89/m91) ----
  const long long crow = bm + wm * 128 + (lane >> 4) * 4;
  const long long ccol = bn + wn * 64 + fr;
  #pragma unroll
  for (int m = 0; m < 8; ++m)
    #pragma unroll
    for (int n = 0; n < 4; ++n)
      #pragma unroll
      for (int r = 0; r < 4; ++r)
        Cb[(crow + m * 16 + r) * ldc + ccol + n * 16] =
            (CT)(acc[m][n][r] * scale);
}

// ---------------------------------------------------------------------------
// row softmax, f16 in/out, IN-PLACE. One 256-thr block per row of T=4096.
// ---------------------------------------------------------------------------
__global__ __launch_bounds__(256) void softmax_rows_f16(
    f16* __restrict__ S, int T)
{
  const size_t row = blockIdx.x;
  const int t      = threadIdx.x;
  f16* s = S + row * (size_t)T;

  f16x8 a = *(const f16x8*)(s + t * 16);
  f16x8 b = *(const f16x8*)(s + t * 16 + 8);

  float v[16];
  float mx = -3.4e38f;
  #pragma unroll
  for (int i = 0; i < 8; ++i) { v[i]     = (float)a[i]; mx = fmaxf(mx, v[i]); }
  #pragma unroll
  for (int i = 0; i < 8; ++i) { v[8 + i] = (float)b[i]; mx = fmaxf(mx, v[8 + i]); }

  __shared__ float red[4];
  #pragma unroll
  for (int o = 32; o > 0; o >>= 1) mx = fmaxf(mx, __shfl_xor(mx, o, 64));
  if ((t & 63) == 0) red[t >> 6] = mx;
  __syncthreads();
  mx = fmaxf(fmaxf(red[0], red[1]), fmaxf(red[2], red[3]));
  __syncthreads();

  float sum = 0.f;
  #pragma unroll
  for (int i = 0; i < 16; ++i) { v[i] = __expf(v[i] - mx); sum += v[i]; }

  #pragma unroll
  for (int o = 32; o > 0; o >>= 1) sum += __shfl_xor(sum, o, 64);
  if ((t & 63) == 0) red[t >> 6] = sum;
  __syncthreads();
  const float inv = 1.f / (red[0] + red[1] + red[2] + red[3]);

  #pragma unroll
  for (int i = 0; i < 8; ++i) a[i] = (f16)(v[i] * inv);
  #pragma unroll
  for (int i = 0; i < 8; ++i) b[i] = (f16)(v[8 + i] * inv);
  *(f16x8*)(s + t * 16)     = a;
  *(f16x8*)(s + t * 16 + 8) = b;
}

// ---------------------------------------------------------------------------
__global__ __launch_bounds__(256) void cvt_f32_f16(
    const float* __restrict__ src, f16* __restrict__ dst, long long n)
{
  long long i = ((long long)blockIdx.x * 256 + threadIdx.x) * 4;
  if (i >= n) return;
  float4 v = *(const float4*)(src + i);
  f16x4 o = {(f16)v.x, (f16)v.y, (f16)v.z, (f16)v.w};
  *(f16x4*)(dst + i) = o;
}

// ---------------------------------------------------------------------------
// Workspace plan:
//   qb  @   0      (64 MiB)  [b][t][h] f16
//   kb  @  64 MiB  (64 MiB)
//   vT  @ 128 MiB  (64 MiB)  [b][h][t] f16
//   xb  @ 192 MiB  (64 MiB)  f16  -- DEAD after projections
//   S   @ 192 MiB  (gs*32 MiB) f16 -- aliases dead xb region
//   wb  @ 192 MiB + max(64, gs*32) MiB  (6 MiB)
// ---------------------------------------------------------------------------
extern "C" void kernel_launch(void* const* d_in, const int* in_sizes, int n_in,
                              void* d_out, int out_size, void* d_ws, size_t ws_size,
                              hipStream_t stream)
{
  const float* x  = (const float*)d_in[0];
  const float* Wq = (const float*)d_in[1];
  const float* Wk = (const float*)d_in[2];
  const float* Wv = (const float*)d_in[3];
  float* out = (float*)d_out;

  const int Bn = 8, T = 4096, Cd = 1024, Hd = 1024;
  const long long BT = (long long)Bn * T;        // 32768

  char* ws = (char*)d_ws;
  const size_t MB = 1u << 20;

  int gs = 0;
  for (int g = 8; g >= 1; g >>= 1) {
    size_t smax = (size_t)(g > 2 ? g * 32 : 64) * MB;
    if (ws_size >= 192 * MB + smax + 6 * MB) { gs = g; break; }
  }
  if (gs == 0) return;
  const size_t sspan = (size_t)(gs > 2 ? gs * 32 : 64) * MB;

  f16* qb  = (f16*)ws;
  f16* kb  = (f16*)(ws + 64 * MB);
  f16* vT  = (f16*)(ws + 128 * MB);              // [b][h][t]
  f16* xb  = (f16*)(ws + 192 * MB);              // dead after projections
  f16* S   = (f16*)(ws + 192 * MB);              // aliases xb
  f16* wqb = (f16*)(ws + 192 * MB + sspan);
  f16* wkb = wqb + (size_t)Hd * Cd;
  f16* wvb = wkb + (size_t)Hd * Cd;

  // 1) fp32 -> f16 converts
  cvt_f32_f16<<<dim3((unsigned)(BT * Cd / 1024)), 256, 0, stream>>>(x, xb, BT * Cd);
  cvt_f32_f16<<<dim3(1024), 256, 0, stream>>>(Wq, wqb, (long long)Hd * Cd);
  cvt_f32_f16<<<dim3(1024), 256, 0, stream>>>(Wk, wkb, (long long)Hd * Cd);
  cvt_f32_f16<<<dim3(1024), 256, 0, stream>>>(Wv, wvb, (long long)Hd * Cd);

  // 2) q = x Wq^T, k = x Wk^T (z-batched: wkb/kb adjacent to wqb/qb)
  gemm_bt256<f16><<<dim3(Hd / 256, (unsigned)(BT / 256), 2), 512, 0, stream>>>(
      xb, wqb, qb, Cd, Cd, Cd, Hd,
      0LL, (long long)Hd * Cd, (long long)BT * Hd, 1.0f);

  // 3) vT_b[h][t] = sum_c Wv[h][c] x_b[t][c]
  gemm_bt256<f16><<<dim3(T / 256, Hd / 256, Bn), 512, 0, stream>>>(
      wvb, xb, vT, Cd, Cd, Cd, T,
      0LL, (long long)T * Cd, (long long)Hd * T, 1.0f);

  // 4-6) attention in batch groups of gs
  for (int b0 = 0; b0 < Bn; b0 += gs) {
    gemm_bt256<f16><<<dim3(T / 256, T / 256, gs), 512, 0, stream>>>(
        qb + (size_t)b0 * T * Hd, kb + (size_t)b0 * T * Hd, S,
        Hd, Hd, Hd, T,
        (long long)T * Hd, (long long)T * Hd, (long long)T * T, 0.03125f);
    softmax_rows_f16<<<dim3((unsigned)(gs * T)), 256, 0, stream>>>(S, T);
    gemm_bt256<float><<<dim3(Hd / 256, T / 256, gs), 512, 0, stream>>>(
        S, vT + (size_t)b0 * Hd * T, out + (size_t)b0 * T * Hd,
        T, T, T, Hd,
        (long long)T * T, (long long)Hd * T, (long long)T * Hd, 1.0f);
  }
  (void)in_sizes; (void)n_in; (void)out_size;
}